// Round 1
// baseline (466.203 us; speedup 1.0000x reference)
//
#include <hip/hip_runtime.h>
#include <hip/hip_bf16.h>
#include <math.h>

#define BATCH 16
#define NN 2048
#define FF 128
#define CC 32
#define HID 512

typedef float v4f __attribute__((ext_vector_type(4)));
typedef short short8 __attribute__((ext_vector_type(8)));

__device__ __forceinline__ unsigned short f2bf(float f) {
  unsigned u = __float_as_uint(f);
  u += 0x7fffu + ((u >> 16) & 1u);
  return (unsigned short)(u >> 16);
}

__device__ __forceinline__ float elu1(float x) {
  return x > 0.f ? x : expm1f(x);
}

// ---------------------------------------------------------------------------
// k_xw: outT[b][c][n] = bf16( src[row][0:K] @ w[K][32] )   (no bias, no act)
// One 16-row MFMA tile per wave. grid = (BATCH*NN/16)/4 blocks of 256.
// ---------------------------------------------------------------------------
template<int K, bool SRC_BF16>
__global__ __launch_bounds__(256)
void k_xw(const void* __restrict__ src, const float* __restrict__ w,
          unsigned short* __restrict__ outT) {
  int t = threadIdx.x;
  int wv = t >> 6, l = t & 63, lo = l & 15, q = l >> 4;
  int rowt = blockIdx.x * 4 + wv;          // 16-row tile id, [0, 2048)
  long row = (long)rowt * 16 + lo;         // this lane's source row (A row)

  // B fragments of w (bf16), kept in registers: B[k=q*8+j][col=lo]
  short8 wf[K / 32][2];
#pragma unroll
  for (int kc = 0; kc < K / 32; ++kc)
#pragma unroll
    for (int h = 0; h < 2; ++h) {
      short8 f;
#pragma unroll
      for (int j = 0; j < 8; ++j)
        f[j] = (short)f2bf(w[(kc * 32 + q * 8 + j) * CC + h * 16 + lo]);
      wf[kc][h] = f;
    }

  v4f acc0 = {0.f, 0.f, 0.f, 0.f}, acc1 = {0.f, 0.f, 0.f, 0.f};
#pragma unroll
  for (int kc = 0; kc < K / 32; ++kc) {
    short8 af;
    if constexpr (SRC_BF16) {
      const unsigned short* sp = (const unsigned short*)src + row * K + kc * 32 + q * 8;
      af = *(const short8*)sp;
    } else {
      const float* sp = (const float*)src + row * K + kc * 32 + q * 8;
      float4 a0 = *(const float4*)sp;
      float4 a1 = *(const float4*)(sp + 4);
      af[0] = (short)f2bf(a0.x); af[1] = (short)f2bf(a0.y);
      af[2] = (short)f2bf(a0.z); af[3] = (short)f2bf(a0.w);
      af[4] = (short)f2bf(a1.x); af[5] = (short)f2bf(a1.y);
      af[6] = (short)f2bf(a1.z); af[7] = (short)f2bf(a1.w);
    }
    acc0 = __builtin_amdgcn_mfma_f32_16x16x32_bf16(af, wf[kc][0], acc0, 0, 0, 0);
    acc1 = __builtin_amdgcn_mfma_f32_16x16x32_bf16(af, wf[kc][1], acc1, 0, 0, 0);
  }

  int b = rowt >> 7;                 // rowt / 128
  int nbase = (rowt & 127) * 16;
#pragma unroll
  for (int r = 0; r < 4; ++r) {
    int n = nbase + q * 4 + r;       // C/D: row = q*4 + reg
    outT[((long)b * CC + lo) * NN + n] = f2bf(acc0[r]);
    outT[((long)b * CC + 16 + lo) * NN + n] = f2bf(acc1[r]);
  }
}

// ---------------------------------------------------------------------------
// k_agg: h_agg[b,n,c] = elu( sum_m a[b,n,m] * hT[b,c,m] + bias[c] )
// mode 0: store bf16 h_out[b][n][32].  mode 1: sum over n -> atomicAdd pooled.
// grid = BATCH * (NN/64) = 512 blocks x 256 threads (4 waves x 16 rows).
// ---------------------------------------------------------------------------
#define SM 512
#define LDS_STRIDE 520   // 512 + 8 bf16 pad: 1040 B row stride, 16B-aligned

__global__ __launch_bounds__(256)
void k_agg(const float* __restrict__ a,
           const unsigned short* __restrict__ hT,   // [B][32][N] bf16
           const float* __restrict__ bias,          // [32]
           unsigned short* __restrict__ h_out,      // mode 0
           float* __restrict__ pooled,              // mode 1
           int mode) {
  __shared__ unsigned short hs[CC * LDS_STRIDE];    // 33280 B

  int t = threadIdx.x;
  int b = blockIdx.x >> 5;
  int rt = blockIdx.x & 31;
  int wv = t >> 6, l = t & 63, lo = l & 15, q = l >> 4;
  int n_wave = rt * 64 + wv * 16;                   // wave's first row

  const float* arow = a + ((long)(b * NN + n_wave + lo)) * NN;

  v4f acc0 = {0.f, 0.f, 0.f, 0.f}, acc1 = {0.f, 0.f, 0.f, 0.f};

  for (int ms = 0; ms < NN; ms += SM) {
    __syncthreads();
    // stage hT[b][0:32][ms:ms+SM] -> LDS (32 KB), uint4-coalesced
    for (int i = t; i < CC * (SM / 8); i += 256) {
      int c = i >> 6;           // / (SM/8)
      int qd = i & 63;
      uint4 v = *(const uint4*)(hT + ((long)b * CC + c) * NN + ms + qd * 8);
      *(uint4*)&hs[c * LDS_STRIDE + qd * 8] = v;
    }
    __syncthreads();

#pragma unroll 4
    for (int mm = 0; mm < SM; mm += 32) {
      int mg = ms + mm + q * 8;
      // A frag: a[n_wave+lo][mg .. mg+7], fp32 -> bf16 RNE
      float4 a0 = *(const float4*)(arow + mg);
      float4 a1 = *(const float4*)(arow + mg + 4);
      short8 af;
      af[0] = (short)f2bf(a0.x); af[1] = (short)f2bf(a0.y);
      af[2] = (short)f2bf(a0.z); af[3] = (short)f2bf(a0.w);
      af[4] = (short)f2bf(a1.x); af[5] = (short)f2bf(a1.y);
      af[6] = (short)f2bf(a1.z); af[7] = (short)f2bf(a1.w);
      // B frags: hs[c][mm + q*8 + j]
      short8 b0 = *(const short8*)&hs[lo * LDS_STRIDE + mm + q * 8];
      short8 b1 = *(const short8*)&hs[(16 + lo) * LDS_STRIDE + mm + q * 8];
      acc0 = __builtin_amdgcn_mfma_f32_16x16x32_bf16(af, b0, acc0, 0, 0, 0);
      acc1 = __builtin_amdgcn_mfma_f32_16x16x32_bf16(af, b1, acc1, 0, 0, 0);
    }
  }

  if (mode == 0) {
#pragma unroll
    for (int r = 0; r < 4; ++r) {
      int n = n_wave + q * 4 + r;
      float v0 = elu1(acc0[r] + bias[lo]);
      float v1 = elu1(acc1[r] + bias[16 + lo]);
      h_out[((long)(b * NN + n)) * CC + lo] = f2bf(v0);
      h_out[((long)(b * NN + n)) * CC + 16 + lo] = f2bf(v1);
    }
  } else {
    float p0 = 0.f, p1 = 0.f;
#pragma unroll
    for (int r = 0; r < 4; ++r) {
      p0 += elu1(acc0[r] + bias[lo]);
      p1 += elu1(acc1[r] + bias[16 + lo]);
    }
    p0 += __shfl_xor(p0, 16, 64);
    p0 += __shfl_xor(p0, 32, 64);
    p1 += __shfl_xor(p1, 16, 64);
    p1 += __shfl_xor(p1, 32, 64);
    if (q == 0) {
      atomicAdd(&pooled[b * CC + lo], p0);
      atomicAdd(&pooled[b * CC + 16 + lo], p1);
    }
  }
}

// ---------------------------------------------------------------------------
// k5: out[b] = sigmoid( relu(pooled[b]@wf1 + bf1) @ wf2 + bf2 )
// ---------------------------------------------------------------------------
__global__ __launch_bounds__(512)
void k5_mlp(const float* __restrict__ pooled, const float* __restrict__ wf1,
            const float* __restrict__ bf1, const float* __restrict__ wf2,
            const float* __restrict__ bf2, float* __restrict__ out) {
  __shared__ float red[HID];
  __shared__ float ps[CC];
  int b = blockIdx.x, j = threadIdx.x;
  if (j < CC) ps[j] = pooled[b * CC + j];
  __syncthreads();
  float acc = bf1[j];
#pragma unroll
  for (int c = 0; c < CC; ++c) acc += ps[c] * wf1[c * HID + j];
  red[j] = fmaxf(acc, 0.f) * wf2[j];
  __syncthreads();
  for (int s = HID / 2; s > 0; s >>= 1) {
    if (j < s) red[j] += red[j + s];
    __syncthreads();
  }
  if (j == 0) out[b] = 1.f / (1.f + expf(-(red[0] + bf2[0])));
}

// ---------------------------------------------------------------------------
extern "C" void kernel_launch(void* const* d_in, const int* in_sizes, int n_in,
                              void* d_out, int out_size, void* d_ws, size_t ws_size,
                              hipStream_t stream) {
  const float* x   = (const float*)d_in[0];
  const float* a   = (const float*)d_in[1];
  const float* w1  = (const float*)d_in[2];
  const float* b1  = (const float*)d_in[3];
  const float* w2  = (const float*)d_in[4];
  const float* b2  = (const float*)d_in[5];
  const float* wf1 = (const float*)d_in[6];
  const float* bf1 = (const float*)d_in[7];
  const float* wf2 = (const float*)d_in[8];
  const float* bf2 = (const float*)d_in[9];
  float* out = (float*)d_out;

  char* ws = (char*)d_ws;
  unsigned short* hT1 = (unsigned short*)ws;                 // [16][32][2048] bf16 = 2 MB
  unsigned short* h1  = (unsigned short*)(ws + (2 << 20));   // [16][2048][32] bf16 = 2 MB
  unsigned short* hT2 = (unsigned short*)ws;                 // reuses hT1 space (K2 done)
  float* pooled = (float*)(ws + (4 << 20));                  // [16][32] fp32

  hipMemsetAsync(pooled, 0, BATCH * CC * sizeof(float), stream);

  // xw1 -> hT1
  k_xw<FF, false><<<512, 256, 0, stream>>>((const void*)x, w1, hT1);
  // layer 1 aggregation + elu -> h1
  k_agg<<<BATCH * (NN / 64), 256, 0, stream>>>(a, hT1, b1, h1, nullptr, 0);
  // h1 @ w2 -> hT2
  k_xw<CC, true><<<512, 256, 0, stream>>>((const void*)h1, w2, hT2);
  // layer 2 aggregation + elu + pool -> pooled
  k_agg<<<BATCH * (NN / 64), 256, 0, stream>>>(a, hT2, b2, nullptr, pooled, 1);
  // MLP head
  k5_mlp<<<BATCH, HID, 0, stream>>>(pooled, wf1, bf1, wf2, bf2, out);
}